// Round 4
// baseline (377.673 us; speedup 1.0000x reference)
//
#include <hip/hip_runtime.h>
#include <stdint.h>

// NeuralMemory (Titans-style) for MI355X / gfx950.
//  norms -> kv/q GEMMs -> grad_fwd (per-chunk MLP fwd/bwd, transposed tiles) ->
//  grad_op (per-chunk outer products -> S) -> double linear scan ->
//  retrieval (register W=w+U) -> combine GEMM. Shift-by-63 via natural indexing.

#define SEQ 4096
#define NTOK 8192

typedef unsigned short u16;
typedef __attribute__((ext_vector_type(8))) short short8;
typedef __attribute__((ext_vector_type(4))) float f32x4;
typedef __attribute__((ext_vector_type(2))) unsigned int u32x2;

__device__ __forceinline__ u16 f2b(float f) {
  union { float f; uint32_t u; } c; c.f = f;
  uint32_t u = c.u;
  uint32_t r = (u + 0x7fffu + ((u >> 16) & 1u)) >> 16;
  return (u16)r;
}
__device__ __forceinline__ float b2f(u16 h) {
  union { uint32_t u; float f; } c; c.u = ((uint32_t)h) << 16;
  return c.f;
}
__device__ __forceinline__ float sigm(float x) { return 1.f / (1.f + __expf(-x)); }
__device__ __forceinline__ uint32_t pk2(float a, float b) {
  return (uint32_t)f2b(a) | ((uint32_t)f2b(b) << 16);
}

// XOR-swizzled element index inside a [rows][128] bf16 LDS tile (16B-granule swizzle)
__device__ __forceinline__ int sidx(int r, int c) {
  return r*128 + ((((c>>3) ^ (r&7))<<3) | (c&7));
}
// contiguous 8-bf16 fragment from row-major [.][128] tile
__device__ __forceinline__ short8 frag_row_lds128(const u16* buf, int row, int ks, int l4) {
  int g = ks*4 + l4;
  return *(const short8*)&buf[row*128 + ((g ^ (row&7))<<3)];
}
// ---- transposed tiles [c:128][r:64], 8-granule XOR swizzle on r ----
// element (c, r) at c*64 + (r ^ ((c&7)<<3)); 8-aligned r-groups stay contiguous.
__device__ __forceinline__ short8 frag_tile(const u16* t, int row, int ks, int l4) {
  return *(const short8*)&t[row*64 + (((ks*4 + l4) ^ (row&7))<<3)];
}
// write 4 consecutive-r values (r0 % 4 == 0) at column c
__device__ __forceinline__ void twr4(u16* t, int c, int r0,
                                     float v0, float v1, float v2, float v3) {
  int addr = c*64 + (r0 ^ ((c&7)<<3));
  u32x2 p; p[0] = pk2(v0, v1); p[1] = pk2(v2, v3);
  *(u32x2*)&t[addr] = p;
}

// ---------------- weight prep ----------------

__global__ __launch_bounds__(256) void transpose_bf16(
    const float* __restrict__ src, u16* __restrict__ dst, int R, int C)
{
  __shared__ u16 tile[64*66];
  int tiles_x = C >> 6;
  int tx = blockIdx.x % tiles_x, ty = blockIdx.x / tiles_x;
  int c0 = tx*64, r0 = ty*64;
#pragma unroll
  for (int it=0; it<16; ++it) {
    int idx = it*256 + threadIdx.x;
    int rr = idx>>6, cc = idx&63;
    tile[cc*66 + rr] = f2b(src[(size_t)(r0+rr)*C + c0+cc]);
  }
  __syncthreads();
#pragma unroll
  for (int it=0; it<16; ++it) {
    int idx = it*256 + threadIdx.x;
    int rr = idx>>6, cc = idx&63;
    dst[(size_t)(c0+rr)*R + r0+cc] = tile[rr*66 + cc];
  }
}

__global__ __launch_bounds__(256) void smallprep(
    const float* __restrict__ w0, const float* __restrict__ w1,
    u16* __restrict__ w0T, u16* __restrict__ w1b, u16* __restrict__ w1T)
{
  int id = blockIdx.x*256 + threadIdx.x;   // 0..16383
  int i = id>>7, j = id&127;
  float a = w0[id], b = w1[id];
  w1b[id] = f2b(b);
  w0T[j*128+i] = f2b(a); w1T[j*128+i] = f2b(b);
}

// ---------------- norms + per-token gates ----------------

__global__ __launch_bounds__(256) void norms_kernel(
    const float* __restrict__ seq, const float* __restrict__ gs,
    const float* __restrict__ gr, const float* __restrict__ wstep,
    const float* __restrict__ wgate, u16* __restrict__ ss,
    u16* __restrict__ sr, float* __restrict__ lr, float* __restrict__ gate)
{
  int t = blockIdx.x; int b = t>>12, pos = t&4095;
  int tid = threadIdx.x;
  const float* row = seq + (size_t)t*1024;
  float x[4]; float ssq = 0.f;
#pragma unroll
  for (int i=0;i<4;++i){ x[i]=row[i*256+tid]; ssq += x[i]*x[i]; }
  for (int m=32;m;m>>=1) ssq += __shfl_xor(ssq, m);
  __shared__ float red[4];
  __shared__ float r2[4][16];
  int wv = tid>>6;
  if ((tid&63)==0) red[wv] = ssq;
  __syncthreads();
  float tot = red[0]+red[1]+red[2]+red[3];
  float inv = rsqrtf(tot*(1.f/1024.f) + 1e-6f);
  float ps[8], pg[8];
#pragma unroll
  for (int h=0;h<8;++h){ ps[h]=0.f; pg[h]=0.f; }
#pragma unroll
  for (int i=0;i<4;++i) {
    int d = i*256+tid;
    float sv = x[i]*inv*gs[d];
    float rv = x[i]*inv*gr[d];
    ss[(size_t)t*1024+d] = f2b(sv);
    sr[(size_t)t*1024+d] = f2b(rv);
#pragma unroll
    for (int h=0;h<8;++h) { ps[h] += sv*wstep[d*8+h]; pg[h] += rv*wgate[d*8+h]; }
  }
#pragma unroll
  for (int h=0;h<8;++h)
    for (int m=32;m;m>>=1){ ps[h] += __shfl_xor(ps[h],m); pg[h] += __shfl_xor(pg[h],m); }
  if ((tid&63)==0) {
#pragma unroll
    for (int h=0;h<8;++h){ r2[wv][h]=ps[h]; r2[wv][8+h]=pg[h]; }
  }
  __syncthreads();
  if (tid < 16) {
    float s = r2[0][tid]+r2[1][tid]+r2[2][tid]+r2[3][tid];
    float sg = sigm(s);
    if (tid<8) lr[((size_t)(b*8+tid))*4096 + pos] = sg*0.01f;
    else gate[((size_t)(b*8+(tid-8)))*4096 + pos] = sg;
  }
}

// ---------------- per-chunk gates from cmean ----------------

__global__ __launch_bounds__(256) void chunkgates_kernel(
    const u16* __restrict__ ss, const float* __restrict__ wmom,
    const float* __restrict__ wdec, float* __restrict__ mg,
    float* __restrict__ d1m)
{
  int bc = blockIdx.x; int b = bc>>6, ch = bc&63;
  size_t t0 = (size_t)(b*4096 + ch*64)*1024;
  int tid = threadIdx.x;
  float cm[4]; cm[0]=cm[1]=cm[2]=cm[3]=0.f;
  for (int tok=0; tok<64; ++tok) {
#pragma unroll
    for (int i=0;i<4;++i)
      cm[i] += b2f(ss[t0 + (size_t)tok*1024 + i*256 + tid]);
  }
  float pm[8], pd[8];
#pragma unroll
  for (int h=0;h<8;++h){ pm[h]=0.f; pd[h]=0.f; }
#pragma unroll
  for (int i=0;i<4;++i) {
    float v = cm[i]*(1.f/64.f);
    int d = i*256+tid;
#pragma unroll
    for (int h=0;h<8;++h){ pm[h]+=v*wmom[d*8+h]; pd[h]+=v*wdec[d*8+h]; }
  }
#pragma unroll
  for (int h=0;h<8;++h)
    for (int m=32;m;m>>=1){ pm[h] += __shfl_xor(pm[h],m); pd[h] += __shfl_xor(pd[h],m); }
  __shared__ float r2[4][16];
  int wv = tid>>6;
  if ((tid&63)==0) {
#pragma unroll
    for (int h=0;h<8;++h){ r2[wv][h]=pm[h]; r2[wv][8+h]=pd[h]; }
  }
  __syncthreads();
  if (tid < 16) {
    float s = r2[0][tid]+r2[1][tid]+r2[2][tid]+r2[3][tid];
    if (tid<8) mg[(b*8+tid)*64 + ch] = sigm(s);
    else d1m[(b*8+(tid-8))*64 + ch] = 1.f - sigm(s);
  }
}

// ---------------- generic bf16 GEMM: C = A(MxK) @ Bt(NxK)^T ----------------

__global__ __launch_bounds__(256) void gemm_bt(
    const u16* __restrict__ A, const u16* __restrict__ Bt,
    void* __restrict__ C, int M, int N, int K, int out_f32)
{
  __shared__ __align__(16) u16 As[128*64];
  __shared__ __align__(16) u16 Bs[128*64];
  int tid = threadIdx.x;
  int wv = tid>>6, lane = tid&63;
  int wr = wv>>1, wc = wv&1;
  int l15 = lane&15, l4 = lane>>4;
  // XCD-aware bijective block swizzle (grid sizes here are all %8==0)
  int nwg = gridDim.x*gridDim.y;
  int wg  = blockIdx.y*gridDim.x + blockIdx.x;
  int cpx = nwg >> 3;
  int swz = (wg & 7)*cpx + (wg >> 3);
  int bx = swz % gridDim.x, by = swz / gridDim.x;
  int brow = by*128, bcol = bx*128;
  f32x4 acc[4][4] = {};
  for (int kt=0; kt<K; kt+=64) {
#pragma unroll
    for (int it=0; it<4; ++it) {
      int gi = it*256 + tid;
      int row = gi>>3, g = gi&7;
      int sg = g ^ (row&7);
      *(short8*)&As[row*64 + sg*8] = *(const short8*)&A[(size_t)(brow+row)*K + kt + g*8];
      *(short8*)&Bs[row*64 + sg*8] = *(const short8*)&Bt[(size_t)(bcol+row)*K + kt + g*8];
    }
    __syncthreads();
#pragma unroll
    for (int ks=0; ks<2; ++ks) {
      short8 af[4], bfr[4];
#pragma unroll
      for (int m=0;m<4;++m) {
        int row = wr*64 + m*16 + l15;
        int g = ks*4 + l4;
        af[m] = *(const short8*)&As[row*64 + ((g ^ (row&7))<<3)];
      }
#pragma unroll
      for (int n=0;n<4;++n) {
        int row = wc*64 + n*16 + l15;
        int g = ks*4 + l4;
        bfr[n] = *(const short8*)&Bs[row*64 + ((g ^ (row&7))<<3)];
      }
#pragma unroll
      for (int m=0;m<4;++m)
#pragma unroll
        for (int n=0;n<4;++n)
          acc[m][n] = __builtin_amdgcn_mfma_f32_16x16x32_bf16(af[m], bfr[n], acc[m][n], 0,0,0);
    }
    __syncthreads();
  }
#pragma unroll
  for (int m=0;m<4;++m) {
#pragma unroll
    for (int n=0;n<4;++n) {
      int col = bcol + wc*64 + n*16 + l15;
#pragma unroll
      for (int j=0;j<4;++j) {
        int row = brow + wr*64 + m*16 + l4*4 + j;
        if (out_f32) ((float*)C)[(size_t)row*N + col] = acc[m][n][j];
        else ((u16*)C)[(size_t)row*N + col] = f2b(acc[m][n][j]);
      }
    }
  }
}

// ---------------- grad_fwd: per-chunk MLP fwd/bwd -> transposed tiles ----------------
// pred = silu(k@w0)@w1 ; dpred = (2/128)*lr*(pred-v) ; da = dpred@w1^T ;
// dx1 = da*silu'(x1). Outputs: kT, aT, dpT, dxT as [c:128][r:64] swizzled tiles.

__global__ __launch_bounds__(256,3) void grad_fwd(
    const u16* __restrict__ kvout, const float* __restrict__ lr,
    const u16* __restrict__ w0T, const u16* __restrict__ w1T,
    const u16* __restrict__ w1b,
    u16* __restrict__ kTg, u16* __restrict__ aTg,
    u16* __restrict__ dpTg, u16* __restrict__ dxTg)
{
  __shared__ __align__(16) u16 bufX[64*128];   // K rows -> a rows -> dpred rows
  __shared__ __align__(16) u16 bufT[128*64];   // kT -> dpT
  __shared__ __align__(16) u16 bufU[128*64];   // aT -> dxT
  __shared__ float lr_s[64];
  int bid = blockIdx.x;
  int bh = bid>>6, ch = bid&63;
  int b = bh>>3, hh = bh&7;
  int tid = threadIdx.x;
  int w = tid>>6, lane = tid&63;
  int l15 = lane&15, l4 = lane>>4;
  size_t t0 = (size_t)(b*4096 + ch*64);
  size_t tout = (size_t)bid*8192;

  // P0: stage K rows -> bufX
#pragma unroll
  for (int it=0; it<4; ++it) {
    int gi = it*256 + tid;
    int row = gi>>4, g = gi&15;
    *(short8*)&bufX[row*128 + ((g ^ (row&7))<<3)] =
      *(const short8*)&kvout[(t0+row)*2048 + hh*128 + g*8];
  }
  if (tid < 64) lr_s[tid] = lr[(size_t)bh*4096 + ch*64 + tid];
  __syncthreads();   // B1

  // P1: x1 = k @ w0 (wave-private rows w*16..+15); kT transpose bufX -> bufT
  f32x4 x1[8] = {};
#pragma unroll
  for (int ks=0; ks<4; ++ks) {
    short8 af = frag_row_lds128(bufX, w*16 + l15, ks, l4);
    int kof = ks*32 + l4*8;
#pragma unroll
    for (int n=0;n<8;++n) {
      short8 bf = *(const short8*)&w0T[(size_t)(n*16+l15)*128 + kof];
      x1[n] = __builtin_amdgcn_mfma_f32_16x16x32_bf16(af, bf, x1[n], 0,0,0);
    }
  }
#pragma unroll
  for (int it=0; it<4; ++it) {
    int task = it*256 + tid;
    int d = task & 127, g8 = task >> 7;
    short8 v;
#pragma unroll
    for (int i=0;i<8;++i) v[i] = (short)bufX[sidx(g8*8+i, d)];
    *(short8*)&bufT[d*64 + ((g8 ^ (d&7))<<3)] = v;
  }
  __syncthreads();   // B2

  // P2: store kT; a = silu(x1) -> bufX rows (own) + aT -> bufU; pred = a @ w1
#pragma unroll
  for (int it=0; it<4; ++it)
    *(short8*)&kTg[tout + (size_t)(it*256+tid)*8] = *(const short8*)&bufT[(it*256+tid)*8];
  int r0 = w*16 + l4*4;
#pragma unroll
  for (int n=0;n<8;++n) {
    int c = n*16 + l15;
    float av[4];
#pragma unroll
    for (int j=0;j<4;++j) { float xv = x1[n][j]; av[j] = xv*sigm(xv); }
    bufX[sidx(r0+0,c)] = f2b(av[0]);
    bufX[sidx(r0+1,c)] = f2b(av[1]);
    bufX[sidx(r0+2,c)] = f2b(av[2]);
    bufX[sidx(r0+3,c)] = f2b(av[3]);
    twr4(bufU, c, r0, av[0], av[1], av[2], av[3]);
  }
  f32x4 pr[8] = {};
#pragma unroll
  for (int ks=0; ks<4; ++ks) {
    short8 af = frag_row_lds128(bufX, w*16 + l15, ks, l4);
    int kof = ks*32 + l4*8;
#pragma unroll
    for (int n=0;n<8;++n) {
      short8 bf = *(const short8*)&w1T[(size_t)(n*16+l15)*128 + kof];
      pr[n] = __builtin_amdgcn_mfma_f32_16x16x32_bf16(af, bf, pr[n], 0,0,0);
    }
  }
  __syncthreads();   // B3

  // P3: store aT; dpred -> bufX rows (own) + dpT -> bufT; da = dpred @ w1^T; dx1
#pragma unroll
  for (int it=0; it<4; ++it)
    *(short8*)&aTg[tout + (size_t)(it*256+tid)*8] = *(const short8*)&bufU[(it*256+tid)*8];
  float dv[8][4];
#pragma unroll
  for (int n=0;n<8;++n) {
    int c = n*16 + l15;
#pragma unroll
    for (int j=0;j<4;++j) {
      float vv = b2f(kvout[(t0+r0+j)*2048 + 1024 + hh*128 + c]);
      dv[n][j] = 0.015625f * lr_s[r0+j] * (pr[n][j] - vv);
    }
    bufX[sidx(r0+0,c)] = f2b(dv[n][0]);
    bufX[sidx(r0+1,c)] = f2b(dv[n][1]);
    bufX[sidx(r0+2,c)] = f2b(dv[n][2]);
    bufX[sidx(r0+3,c)] = f2b(dv[n][3]);
    twr4(bufT, c, r0, dv[n][0], dv[n][1], dv[n][2], dv[n][3]);
  }
  f32x4 da[8] = {};
#pragma unroll
  for (int ks=0; ks<4; ++ks) {
    short8 af = frag_row_lds128(bufX, w*16 + l15, ks, l4);
    int kof = ks*32 + l4*8;
#pragma unroll
    for (int n=0;n<8;++n) {
      short8 bf = *(const short8*)&w1b[(size_t)(n*16+l15)*128 + kof];
      da[n] = __builtin_amdgcn_mfma_f32_16x16x32_bf16(af, bf, da[n], 0,0,0);
    }
  }
  float dx[8][4];
#pragma unroll
  for (int n=0;n<8;++n)
#pragma unroll
    for (int j=0;j<4;++j) {
      float xv = x1[n][j];
      float sg = sigm(xv);
      dx[n][j] = da[n][j]*(sg*(1.f + xv*(1.f - sg)));
    }
  __syncthreads();   // B4

  // P4: store dpT; dxT -> bufU
#pragma unroll
  for (int it=0; it<4; ++it)
    *(short8*)&dpTg[tout + (size_t)(it*256+tid)*8] = *(const short8*)&bufT[(it*256+tid)*8];
#pragma unroll
  for (int n=0;n<8;++n)
    twr4(bufU, n*16 + l15, r0, dx[n][0], dx[n][1], dx[n][2], dx[n][3]);
  __syncthreads();   // B5

  // P5: store dxT
#pragma unroll
  for (int it=0; it<4; ++it)
    *(short8*)&dxTg[tout + (size_t)(it*256+tid)*8] = *(const short8*)&bufU[(it*256+tid)*8];
}

// ---------------- grad_op: per-chunk outer products -> S (transposed, bf16) ----------
// op=0: S1T[eo][em] = -sum_r dpred[r][eo] a[r][em]
// op=1: S0T[em][ei] = -sum_r dx1[r][em]  k[r][ei]

__global__ __launch_bounds__(256) void grad_op(
    const u16* __restrict__ dpT, const u16* __restrict__ aT,
    const u16* __restrict__ dxT, const u16* __restrict__ kT,
    u16* __restrict__ S)
{
  __shared__ __align__(16) u16 lds[16384];
  int bid = blockIdx.x;
  int op = bid >> 10;
  int sub = bid & 1023, bh = sub>>6, ch = sub&63;
  size_t tin = (size_t)sub*8192;
  const u16* Ain = op ? (dxT + tin) : (dpT + tin);
  const u16* Bin = op ? (kT  + tin) : (aT  + tin);
  int tid = threadIdx.x;
  int w = tid>>6, lane = tid&63;
  int l15 = lane&15, l4 = lane>>4;

  // load tiles (verbatim, layout preserved)
#pragma unroll
  for (int it=0; it<4; ++it) {
    ((short8*)lds)[it*256+tid]        = ((const short8*)Ain)[it*256+tid];
    ((short8*)(lds+8192))[it*256+tid] = ((const short8*)Bin)[it*256+tid];
  }
  __syncthreads();

  f32x4 g[2][8] = {};
#pragma unroll
  for (int ks=0; ks<2; ++ks) {
    short8 af[2];
#pragma unroll
    for (int mi=0; mi<2; ++mi)
      af[mi] = frag_tile(lds, w*32 + mi*16 + l15, ks, l4);
#pragma unroll
    for (int n=0;n<8;++n) {
      short8 bf = frag_tile(lds+8192, n*16 + l15, ks, l4);
#pragma unroll
      for (int mi=0;mi<2;++mi)
        g[mi][n] = __builtin_amdgcn_mfma_f32_16x16x32_bf16(af[mi], bf, g[mi][n], 0,0,0);
    }
  }
  __syncthreads();

  // stage -g into lds ([128][128], sidx swizzle)
#pragma unroll
  for (int mi=0;mi<2;++mi)
#pragma unroll
    for (int n=0;n<8;++n)
#pragma unroll
      for (int j=0;j<4;++j) {
        int m = w*32 + mi*16 + l4*4 + j, c = n*16 + l15;
        lds[sidx(m,c)] = f2b(-g[mi][n][j]);
      }
  __syncthreads();

  // coalesced bulk store
  u16* Sout = S + ((size_t)((op ? bh : 16+bh))*64 + ch)*16384;
#pragma unroll
  for (int it=0; it<8; ++it) {
    int task = it*256 + tid;
    int m = task>>4, gg = task&15;
    *(short8*)&Sout[m*128 + gg*8] = *(const short8*)&lds[m*128 + ((gg ^ (m&7))<<3)];
  }
}

// ---------------- double linear-recurrence scan over chunks (in place, bf16) ----------------

__global__ __launch_bounds__(256) void scan_kernel(
    u16* __restrict__ S, const float* __restrict__ mg, const float* __restrict__ d1m)
{
  int bidx = blockIdx.x;              // (m*16+bh)*64 + eblk
  int eblk = bidx & 63;
  int mbh = bidx >> 6;                // 0..31
  int bh = mbh & 15;
  int e = eblk*256 + threadIdx.x;
  u16* base = S + (size_t)mbh*64*16384 + e;
  const float* g1 = mg + bh*64;
  const float* g2 = d1m + bh*64;
  float mom = 0.f, upd = 0.f;
  for (int c2=0; c2<64; ++c2) {
    float s = b2f(base[(size_t)c2*16384]);
    mom = g1[c2]*mom + s;            // momentum scan
    upd = g2[c2]*upd + mom;          // update scan
    base[(size_t)c2*16384] = f2b(upd);
  }
}

// ---------------- per-chunk retrieval (W = w + U summed in registers) ----------------

__global__ __launch_bounds__(256) void retrieve_kernel(
    const u16* __restrict__ qn, const u16* __restrict__ U,
    const u16* __restrict__ w0T, const u16* __restrict__ w1T,
    const float* __restrict__ gamma, const float* __restrict__ gate,
    u16* __restrict__ vals)
{
  __shared__ __align__(16) u16 QA[64*128];    // Q tile, later reused for silu(x)
  int bid = blockIdx.x; int bh = bid>>6, ch = bid&63;
  int b = bh>>3, h = bh&7;
  int tid = threadIdx.x;
  int w = tid>>6, lane = tid&63;
  int l15 = lane&15, l4 = lane>>4;
  const u16* U0 = U + ((size_t)bh*64 + ch)*16384;
  const u16* U1 = U + ((size_t)(16+bh)*64 + ch)*16384;
#pragma unroll
  for (int it=0; it<4; ++it) {
    int gi = it*256 + tid; int row = gi>>4, g = gi&15;
    int posn = ch*64 + row + 63;       // natural position of shifted query row
    short8 v;
    if (posn < 4096) v = *(const short8*)&qn[((size_t)(b*4096+posn))*1024 + h*128 + g*8];
    else {
#pragma unroll
      for (int i=0;i<8;++i) v[i]=0;
    }
    *(short8*)&QA[row*128 + ((g ^ (row&7))<<3)] = v;
  }
  __syncthreads();
  // x = q @ (w0+u0): B-fragments built in registers from bf16 w0T + U0T
  f32x4 xx[8] = {};
#pragma unroll
  for (int ks=0; ks<4; ++ks) {
    short8 af = frag_row_lds128(QA, w*16 + l15, ks, l4);
    int kof = ks*32 + l4*8;
#pragma unroll
    for (int n=0;n<8;++n) {
      size_t o = (size_t)(n*16+l15)*128 + kof;
      short8 wa = *(const short8*)&w0T[o];
      short8 ua = *(const short8*)&U0[o];
      short8 bf;
#pragma unroll
      for (int i=0;i<8;++i) bf[i] = (short)f2b(b2f((u16)(short)wa[i]) + b2f((u16)(short)ua[i]));
      xx[n] = __builtin_amdgcn_mfma_f32_16x16x32_bf16(af, bf, xx[n], 0,0,0);
    }
  }
  // silu(x) overwrites own rows of QA
  int r0 = w*16 + l4*4;
#pragma unroll
  for (int n=0;n<8;++n) {
    int c = n*16 + l15;
#pragma unroll
    for (int j=0;j<4;++j) {
      float xv = xx[n][j];
      QA[sidx(r0+j,c)] = f2b(xv * sigm(xv));
    }
  }
  // vals = silu(x) @ (w1+u1)
  f32x4 vv[8] = {};
#pragma unroll
  for (int ks=0; ks<4; ++ks) {
    short8 af = frag_row_lds128(QA, w*16 + l15, ks, l4);
    int kof = ks*32 + l4*8;
#pragma unroll
    for (int n=0;n<8;++n) {
      size_t o = (size_t)(n*16+l15)*128 + kof;
      short8 wa = *(const short8*)&w1T[o];
      short8 ua = *(const short8*)&U1[o];
      short8 bf;
#pragma unroll
      for (int i=0;i<8;++i) bf[i] = (short)f2b(b2f((u16)(short)wa[i]) + b2f((u16)(short)ua[i]));
      vv[n] = __builtin_amdgcn_mfma_f32_16x16x32_bf16(af, bf, vv[n], 0,0,0);
    }
  }
  // epilogue: rmsnorm over dh, *(1+gamma), *gate, store at natural pos
#pragma unroll
  for (int j=0;j<4;++j) {
    float ssq = 0.f;
#pragma unroll
    for (int n=0;n<8;++n) ssq += vv[n][j]*vv[n][j];
    ssq += __shfl_xor(ssq,1); ssq += __shfl_xor(ssq,2);
    ssq += __shfl_xor(ssq,4); ssq += __shfl_xor(ssq,8);
    float rms = rsqrtf(ssq*(1.f/128.f) + 1e-6f);
    int r = r0 + j;
    int posn = ch*64 + r + 63;
    if (posn < 4096) {
      float gt = gate[(size_t)bh*4096 + posn];
      size_t orow = ((size_t)(b*4096+posn))*1024 + h*128;
#pragma unroll
      for (int n=0;n<8;++n) {
        int c = n*16 + l15;
        vals[orow + c] = f2b(vv[n][j]*rms*(1.f + gamma[h*128+c])*gt);
      }
    }
  }
}

extern "C" void kernel_launch(void* const* d_in, const int* in_sizes, int n_in,
                              void* d_out, int out_size, void* d_ws, size_t ws_size,
                              hipStream_t stream) {
  const float* seq    = (const float*)d_in[0];
  const float* gstore = (const float*)d_in[1];
  const float* gret   = (const float*)d_in[2];
  const float* wkv    = (const float*)d_in[3];
  const float* wq     = (const float*)d_in[4];
  const float* wstep  = (const float*)d_in[5];
  const float* wmom   = (const float*)d_in[6];
  const float* wdec   = (const float*)d_in[7];
  const float* wgate  = (const float*)d_in[8];
  const float* wcomb  = (const float*)d_in[9];
  const float* gamma  = (const float*)d_in[10];
  const float* w0f    = (const float*)d_in[11];
  const float* w1f    = (const float*)d_in[12];
  float* out = (float*)d_out;
  (void)in_sizes; (void)n_in; (void)out_size; (void)ws_size;

  char* p = (char*)d_ws;
  size_t off = 0;
  auto alloc = [&](size_t bytes) -> void* {
    void* r = p + off; off += (bytes + 255) & ~(size_t)255; return r;
  };
  u16* wkvT   = (u16*)alloc((size_t)2048*1024*2);
  u16* wqT    = (u16*)alloc((size_t)1024*1024*2);
  u16* wcombT = (u16*)alloc((size_t)1024*1024*2);
  u16* w0T    = (u16*)alloc(16384*2);
  u16* w1b    = (u16*)alloc(16384*2);
  u16* w1T    = (u16*)alloc(16384*2);
  u16* ss     = (u16*)alloc((size_t)NTOK*1024*2);
  u16* sr     = (u16*)alloc((size_t)NTOK*1024*2);
  u16* kvout  = (u16*)alloc((size_t)NTOK*2048*2);
  u16* qn     = (u16*)alloc((size_t)NTOK*1024*2);
  u16* vals   = (u16*)alloc((size_t)NTOK*1024*2);
  float* lr   = (float*)alloc((size_t)16*4096*4);
  float* gate = (float*)alloc((size_t)16*4096*4);
  float* mg   = (float*)alloc(1024*4);
  float* d1m  = (float*)alloc(1024*4);
  u16* S      = (u16*)alloc((size_t)32*64*16384*2);
  u16* kTg    = (u16*)alloc((size_t)1024*8192*2);
  u16* aTg    = (u16*)alloc((size_t)1024*8192*2);
  u16* dpTg   = (u16*)alloc((size_t)1024*8192*2);
  u16* dxTg   = (u16*)alloc((size_t)1024*8192*2);

  transpose_bf16<<<dim3(512),dim3(256),0,stream>>>(wkv, wkvT, 1024, 2048);
  transpose_bf16<<<dim3(256),dim3(256),0,stream>>>(wq, wqT, 1024, 1024);
  transpose_bf16<<<dim3(256),dim3(256),0,stream>>>(wcomb, wcombT, 1024, 1024);
  smallprep<<<dim3(64),dim3(256),0,stream>>>(w0f, w1f, w0T, w1b, w1T);
  norms_kernel<<<dim3(NTOK),dim3(256),0,stream>>>(seq, gstore, gret, wstep, wgate, ss, sr, lr, gate);
  chunkgates_kernel<<<dim3(128),dim3(256),0,stream>>>(ss, wmom, wdec, mg, d1m);
  gemm_bt<<<dim3(16,64),dim3(256),0,stream>>>(ss, wkvT, kvout, 8192, 2048, 1024, 0);
  gemm_bt<<<dim3(8,64),dim3(256),0,stream>>>(sr, wqT, qn, 8192, 1024, 1024, 0);
  grad_fwd<<<dim3(1024),dim3(256),0,stream>>>(kvout, lr, w0T, w1T, w1b, kTg, aTg, dpTg, dxTg);
  grad_op<<<dim3(2048),dim3(256),0,stream>>>(dpTg, aTg, dxTg, kTg, S);
  scan_kernel<<<dim3(2048),dim3(256),0,stream>>>(S, mg, d1m);
  hipMemsetAsync(vals, 0, (size_t)NTOK*1024*2, stream);
  retrieve_kernel<<<dim3(1024),dim3(256),0,stream>>>(qn, S, w0T, w1T, gamma, gate, vals);
  gemm_bt<<<dim3(8,64),dim3(256),0,stream>>>(vals, wcombT, out, 8192, 1024, 1024, 1);
}

// Round 5
// 332.730 us; speedup vs baseline: 1.1351x; 1.1351x over previous
//
#include <hip/hip_runtime.h>
#include <stdint.h>

// NeuralMemory (Titans-style) for MI355X / gfx950.
//  norms -> kv GEMM (+kT epilogue) / q GEMM -> mlp_fwd (barrier-free per-wave
//  MLP fwd/bwd -> aT/dpT/dxT) -> grad_op (outer products -> S) ->
//  scan (folds w+U -> W) -> retrieve (direct W loads, barrier-free) ->
//  combine GEMM. Shift-by-63 via natural indexing.

#define SEQ 4096
#define NTOK 8192

typedef unsigned short u16;
typedef __attribute__((ext_vector_type(8))) short short8;
typedef __attribute__((ext_vector_type(4))) float f32x4;
typedef __attribute__((ext_vector_type(2))) unsigned int u32x2;

__device__ __forceinline__ u16 f2b(float f) {
  union { float f; uint32_t u; } c; c.f = f;
  uint32_t u = c.u;
  uint32_t r = (u + 0x7fffu + ((u >> 16) & 1u)) >> 16;
  return (u16)r;
}
__device__ __forceinline__ float b2f(u16 h) {
  union { uint32_t u; float f; } c; c.u = ((uint32_t)h) << 16;
  return c.f;
}
__device__ __forceinline__ float sigm(float x) { return 1.f / (1.f + __expf(-x)); }
__device__ __forceinline__ uint32_t pk2(float a, float b) {
  return (uint32_t)f2b(a) | ((uint32_t)f2b(b) << 16);
}

// XOR-swizzled element index inside a [rows][128] bf16 LDS tile (16B-granule swizzle)
__device__ __forceinline__ int sidx(int r, int c) {
  return r*128 + ((((c>>3) ^ (r&7))<<3) | (c&7));
}
// contiguous 8-bf16 fragment from row-major [.][128] tile
__device__ __forceinline__ short8 frag_row_lds128(const u16* buf, int row, int ks, int l4) {
  int g = ks*4 + l4;
  return *(const short8*)&buf[row*128 + ((g ^ (row&7))<<3)];
}
// ---- transposed tiles [c:128][r:64], 8-granule XOR swizzle on r ----
__device__ __forceinline__ short8 frag_tile(const u16* t, int row, int ks, int l4) {
  return *(const short8*)&t[row*64 + (((ks*4 + l4) ^ (row&7))<<3)];
}
// T-layout element offset for a 4-row-aligned pack at column c, rows r0..r0+3
__device__ __forceinline__ int taddr(int c, int r0) {
  return c*64 + (r0 ^ ((c&7)<<3));
}

// ---------------- weight prep ----------------

__global__ __launch_bounds__(256) void transpose_bf16(
    const float* __restrict__ src, u16* __restrict__ dst, int R, int C)
{
  __shared__ u16 tile[64*66];
  int tiles_x = C >> 6;
  int tx = blockIdx.x % tiles_x, ty = blockIdx.x / tiles_x;
  int c0 = tx*64, r0 = ty*64;
#pragma unroll
  for (int it=0; it<16; ++it) {
    int idx = it*256 + threadIdx.x;
    int rr = idx>>6, cc = idx&63;
    tile[cc*66 + rr] = f2b(src[(size_t)(r0+rr)*C + c0+cc]);
  }
  __syncthreads();
#pragma unroll
  for (int it=0; it<16; ++it) {
    int idx = it*256 + threadIdx.x;
    int rr = idx>>6, cc = idx&63;
    dst[(size_t)(c0+rr)*R + r0+cc] = tile[rr*66 + cc];
  }
}

__global__ __launch_bounds__(256) void smallprep(
    const float* __restrict__ w0, const float* __restrict__ w1,
    u16* __restrict__ w0T, u16* __restrict__ w1b, u16* __restrict__ w1T)
{
  int id = blockIdx.x*256 + threadIdx.x;   // 0..16383
  int i = id>>7, j = id&127;
  float a = w0[id], b = w1[id];
  w1b[id] = f2b(b);
  w0T[j*128+i] = f2b(a); w1T[j*128+i] = f2b(b);
}

// ---------------- norms + per-token gates ----------------

__global__ __launch_bounds__(256) void norms_kernel(
    const float* __restrict__ seq, const float* __restrict__ gs,
    const float* __restrict__ gr, const float* __restrict__ wstep,
    const float* __restrict__ wgate, u16* __restrict__ ss,
    u16* __restrict__ sr, float* __restrict__ lr, float* __restrict__ gate)
{
  int t = blockIdx.x; int b = t>>12, pos = t&4095;
  int tid = threadIdx.x;
  const float* row = seq + (size_t)t*1024;
  float x[4]; float ssq = 0.f;
#pragma unroll
  for (int i=0;i<4;++i){ x[i]=row[i*256+tid]; ssq += x[i]*x[i]; }
  for (int m=32;m;m>>=1) ssq += __shfl_xor(ssq, m);
  __shared__ float red[4];
  __shared__ float r2[4][16];
  int wv = tid>>6;
  if ((tid&63)==0) red[wv] = ssq;
  __syncthreads();
  float tot = red[0]+red[1]+red[2]+red[3];
  float inv = rsqrtf(tot*(1.f/1024.f) + 1e-6f);
  float ps[8], pg[8];
#pragma unroll
  for (int h=0;h<8;++h){ ps[h]=0.f; pg[h]=0.f; }
#pragma unroll
  for (int i=0;i<4;++i) {
    int d = i*256+tid;
    float sv = x[i]*inv*gs[d];
    float rv = x[i]*inv*gr[d];
    ss[(size_t)t*1024+d] = f2b(sv);
    sr[(size_t)t*1024+d] = f2b(rv);
#pragma unroll
    for (int h=0;h<8;++h) { ps[h] += sv*wstep[d*8+h]; pg[h] += rv*wgate[d*8+h]; }
  }
#pragma unroll
  for (int h=0;h<8;++h)
    for (int m=32;m;m>>=1){ ps[h] += __shfl_xor(ps[h],m); pg[h] += __shfl_xor(pg[h],m); }
  if ((tid&63)==0) {
#pragma unroll
    for (int h=0;h<8;++h){ r2[wv][h]=ps[h]; r2[wv][8+h]=pg[h]; }
  }
  __syncthreads();
  if (tid < 16) {
    float s = r2[0][tid]+r2[1][tid]+r2[2][tid]+r2[3][tid];
    float sg = sigm(s);
    if (tid<8) lr[((size_t)(b*8+tid))*4096 + pos] = sg*0.01f;
    else gate[((size_t)(b*8+(tid-8)))*4096 + pos] = sg;
  }
}

// ---------------- per-chunk gates from cmean ----------------

__global__ __launch_bounds__(256) void chunkgates_kernel(
    const u16* __restrict__ ss, const float* __restrict__ wmom,
    const float* __restrict__ wdec, float* __restrict__ mg,
    float* __restrict__ d1m)
{
  int bc = blockIdx.x; int b = bc>>6, ch = bc&63;
  size_t t0 = (size_t)(b*4096 + ch*64)*1024;
  int tid = threadIdx.x;
  float cm[4]; cm[0]=cm[1]=cm[2]=cm[3]=0.f;
  for (int tok=0; tok<64; ++tok) {
#pragma unroll
    for (int i=0;i<4;++i)
      cm[i] += b2f(ss[t0 + (size_t)tok*1024 + i*256 + tid]);
  }
  float pm[8], pd[8];
#pragma unroll
  for (int h=0;h<8;++h){ pm[h]=0.f; pd[h]=0.f; }
#pragma unroll
  for (int i=0;i<4;++i) {
    float v = cm[i]*(1.f/64.f);
    int d = i*256+tid;
#pragma unroll
    for (int h=0;h<8;++h){ pm[h]+=v*wmom[d*8+h]; pd[h]+=v*wdec[d*8+h]; }
  }
#pragma unroll
  for (int h=0;h<8;++h)
    for (int m=32;m;m>>=1){ pm[h] += __shfl_xor(pm[h],m); pd[h] += __shfl_xor(pd[h],m); }
  __shared__ float r2[4][16];
  int wv = tid>>6;
  if ((tid&63)==0) {
#pragma unroll
    for (int h=0;h<8;++h){ r2[wv][h]=pm[h]; r2[wv][8+h]=pd[h]; }
  }
  __syncthreads();
  if (tid < 16) {
    float s = r2[0][tid]+r2[1][tid]+r2[2][tid]+r2[3][tid];
    if (tid<8) mg[(b*8+tid)*64 + ch] = sigm(s);
    else d1m[(b*8+(tid-8))*64 + ch] = 1.f - sigm(s);
  }
}

// ---------------- generic bf16 GEMM: C = A(MxK) @ Bt(NxK)^T ----------------
// kvT != nullptr (kv GEMM only): keys half (col<1024) additionally stored as
// per-chunk transposed tiles kT[chunk][d:128][r:64] (XOR-swizzled).

__global__ __launch_bounds__(256) void gemm_bt(
    const u16* __restrict__ A, const u16* __restrict__ Bt,
    void* __restrict__ C, int M, int N, int K, int out_f32,
    u16* __restrict__ kvT)
{
  __shared__ __align__(16) u16 As[128*64];
  __shared__ __align__(16) u16 Bs[128*64];
  int tid = threadIdx.x;
  int wv = tid>>6, lane = tid&63;
  int wr = wv>>1, wc = wv&1;
  int l15 = lane&15, l4 = lane>>4;
  // XCD-aware bijective block swizzle (grid sizes here are all %8==0)
  int nwg = gridDim.x*gridDim.y;
  int wg  = blockIdx.y*gridDim.x + blockIdx.x;
  int cpx = nwg >> 3;
  int swz = (wg & 7)*cpx + (wg >> 3);
  int bx = swz % gridDim.x, by = swz / gridDim.x;
  int brow = by*128, bcol = bx*128;
  f32x4 acc[4][4] = {};
  for (int kt=0; kt<K; kt+=64) {
#pragma unroll
    for (int it=0; it<4; ++it) {
      int gi = it*256 + tid;
      int row = gi>>3, g = gi&7;
      int sg = g ^ (row&7);
      *(short8*)&As[row*64 + sg*8] = *(const short8*)&A[(size_t)(brow+row)*K + kt + g*8];
      *(short8*)&Bs[row*64 + sg*8] = *(const short8*)&Bt[(size_t)(bcol+row)*K + kt + g*8];
    }
    __syncthreads();
#pragma unroll
    for (int ks=0; ks<2; ++ks) {
      short8 af[4], bfr[4];
#pragma unroll
      for (int m=0;m<4;++m) {
        int row = wr*64 + m*16 + l15;
        int g = ks*4 + l4;
        af[m] = *(const short8*)&As[row*64 + ((g ^ (row&7))<<3)];
      }
#pragma unroll
      for (int n=0;n<4;++n) {
        int row = wc*64 + n*16 + l15;
        int g = ks*4 + l4;
        bfr[n] = *(const short8*)&Bs[row*64 + ((g ^ (row&7))<<3)];
      }
#pragma unroll
      for (int m=0;m<4;++m)
#pragma unroll
        for (int n=0;n<4;++n)
          acc[m][n] = __builtin_amdgcn_mfma_f32_16x16x32_bf16(af[m], bfr[n], acc[m][n], 0,0,0);
    }
    __syncthreads();
  }
#pragma unroll
  for (int m=0;m<4;++m) {
#pragma unroll
    for (int n=0;n<4;++n) {
      int col = bcol + wc*64 + n*16 + l15;
#pragma unroll
      for (int j=0;j<4;++j) {
        int row = brow + wr*64 + m*16 + l4*4 + j;
        if (out_f32) ((float*)C)[(size_t)row*N + col] = acc[m][n][j];
        else ((u16*)C)[(size_t)row*N + col] = f2b(acc[m][n][j]);
      }
    }
  }
  if (kvT) {
#pragma unroll
    for (int m=0;m<4;++m) {
#pragma unroll
      for (int n=0;n<4;++n) {
        int col = bcol + wc*64 + n*16 + l15;
        if (col < 1024) {
          int row0 = brow + wr*64 + m*16 + l4*4;
          int d = col & 127;
          int chunk = ((row0>>12)*8 + (col>>7))*64 + ((row0&4095)>>6);
          int rr = row0 & 63;
          u32x2 p; p[0] = pk2(acc[m][n][0], acc[m][n][1]);
                   p[1] = pk2(acc[m][n][2], acc[m][n][3]);
          *(u32x2*)&kvT[(size_t)chunk*8192 + taddr(d, rr)] = p;
        }
      }
    }
  }
}

// ---------------- mlp_fwd: barrier-free per-wave MLP fwd/bwd ----------------
// Wave w owns chunk rows w*16..+15. Outputs aT/dpT/dxT ([c:128][r:64] swizzled,
// straight to global). kT comes from the kv GEMM epilogue.

__global__ __launch_bounds__(256) void mlp_fwd(
    const u16* __restrict__ kvout, const float* __restrict__ lr,
    const u16* __restrict__ w0T, const u16* __restrict__ w1T,
    const u16* __restrict__ w1b,
    u16* __restrict__ aTg, u16* __restrict__ dpTg, u16* __restrict__ dxTg)
{
  __shared__ __align__(16) u16 abuf[64*128];   // a rows -> dpred rows (wave-private)
  __shared__ __align__(16) u16 vbuf[64*128];   // V rows (wave-private)
  int bid = blockIdx.x;
  int bh = bid>>6, ch = bid&63;
  int b = bh>>3, hh = bh&7;
  int tid = threadIdx.x;
  int w = tid>>6, lane = tid&63;
  int l15 = lane&15, l4 = lane>>4;
  size_t t0 = (size_t)(b*4096 + ch*64);
  size_t tout = (size_t)bid*8192;

  // stage this wave's 16 V rows (coalesced 16B, sidx swizzle)
#pragma unroll
  for (int it=0; it<4; ++it) {
    int task = it*64 + lane;
    int rloc = w*16 + (task>>4), g = task&15;
    *(short8*)&vbuf[rloc*128 + ((g ^ (rloc&7))<<3)] =
      *(const short8*)&kvout[(t0+rloc)*2048 + 1024 + hh*128 + g*8];
  }
  int r0 = w*16 + l4*4;
  f32x4 lrv = *(const f32x4*)&lr[(size_t)bh*4096 + ch*64 + r0];

  // x1 = k @ w0 : A-frags direct from global (in-register reuse across n)
  f32x4 x1[8] = {};
#pragma unroll
  for (int ks=0; ks<4; ++ks) {
    short8 af = *(const short8*)&kvout[(t0 + w*16 + l15)*2048 + hh*128 + ks*32 + l4*8];
    int kof = ks*32 + l4*8;
#pragma unroll
    for (int n=0;n<8;++n) {
      short8 bf = *(const short8*)&w0T[(size_t)(n*16+l15)*128 + kof];
      x1[n] = __builtin_amdgcn_mfma_f32_16x16x32_bf16(af, bf, x1[n], 0,0,0);
    }
  }
  // a = silu(x1): own LDS rows + aT global
#pragma unroll
  for (int n=0;n<8;++n) {
    int c = n*16 + l15;
    float av[4];
#pragma unroll
    for (int j=0;j<4;++j){ float xv = x1[n][j]; av[j] = xv*sigm(xv); }
    abuf[sidx(r0+0,c)] = f2b(av[0]);
    abuf[sidx(r0+1,c)] = f2b(av[1]);
    abuf[sidx(r0+2,c)] = f2b(av[2]);
    abuf[sidx(r0+3,c)] = f2b(av[3]);
    u32x2 p; p[0] = pk2(av[0],av[1]); p[1] = pk2(av[2],av[3]);
    *(u32x2*)&aTg[tout + taddr(c, r0)] = p;
  }
  // pred = a @ w1 (reads own rows only)
  f32x4 pr[8] = {};
#pragma unroll
  for (int ks=0; ks<4; ++ks) {
    short8 af = frag_row_lds128(abuf, w*16 + l15, ks, l4);
    int kof = ks*32 + l4*8;
#pragma unroll
    for (int n=0;n<8;++n) {
      short8 bf = *(const short8*)&w1T[(size_t)(n*16+l15)*128 + kof];
      pr[n] = __builtin_amdgcn_mfma_f32_16x16x32_bf16(af, bf, pr[n], 0,0,0);
    }
  }
  // dpred = (2/128)*lr*(pred - v): own LDS rows (overwrite a) + dpT global
#pragma unroll
  for (int n=0;n<8;++n) {
    int c = n*16 + l15;
    float dv[4];
#pragma unroll
    for (int j=0;j<4;++j)
      dv[j] = 0.015625f * lrv[j] * (pr[n][j] - b2f(vbuf[sidx(r0+j,c)]));
    abuf[sidx(r0+0,c)] = f2b(dv[0]);
    abuf[sidx(r0+1,c)] = f2b(dv[1]);
    abuf[sidx(r0+2,c)] = f2b(dv[2]);
    abuf[sidx(r0+3,c)] = f2b(dv[3]);
    u32x2 p; p[0] = pk2(dv[0],dv[1]); p[1] = pk2(dv[2],dv[3]);
    *(u32x2*)&dpTg[tout + taddr(c, r0)] = p;
  }
  // da = dpred @ w1^T (Bt = w1 row-major)
  f32x4 da[8] = {};
#pragma unroll
  for (int ks=0; ks<4; ++ks) {
    short8 af = frag_row_lds128(abuf, w*16 + l15, ks, l4);
    int kof = ks*32 + l4*8;
#pragma unroll
    for (int n=0;n<8;++n) {
      short8 bf = *(const short8*)&w1b[(size_t)(n*16+l15)*128 + kof];
      da[n] = __builtin_amdgcn_mfma_f32_16x16x32_bf16(af, bf, da[n], 0,0,0);
    }
  }
  // dx1 = da * silu'(x1) -> dxT global
#pragma unroll
  for (int n=0;n<8;++n) {
    int c = n*16 + l15;
    float d[4];
#pragma unroll
    for (int j=0;j<4;++j) {
      float xv = x1[n][j];
      float sg = sigm(xv);
      d[j] = da[n][j]*(sg*(1.f + xv*(1.f - sg)));
    }
    u32x2 p; p[0] = pk2(d[0],d[1]); p[1] = pk2(d[2],d[3]);
    *(u32x2*)&dxTg[tout + taddr(c, r0)] = p;
  }
}

// ---------------- grad_op: per-chunk outer products -> S (transposed, bf16) ----------
// op=0: S1T[eo][em] = -sum_r dpred[r][eo] a[r][em]   -> S upper half
// op=1: S0T[em][ei] = -sum_r dx1[r][em]  k[r][ei]    -> S lower half

__global__ __launch_bounds__(256) void grad_op(
    const u16* __restrict__ dpT, const u16* __restrict__ aT,
    const u16* __restrict__ dxT, const u16* __restrict__ kT,
    u16* __restrict__ S)
{
  __shared__ __align__(16) u16 lds[16384];
  int bid = blockIdx.x;
  int op = bid >> 10;
  int sub = bid & 1023, bh = sub>>6, ch = sub&63;
  size_t tin = (size_t)sub*8192;
  const u16* Ain = op ? (dxT + tin) : (dpT + tin);
  const u16* Bin = op ? (kT  + tin) : (aT  + tin);
  int tid = threadIdx.x;
  int w = tid>>6, lane = tid&63;
  int l15 = lane&15, l4 = lane>>4;

#pragma unroll
  for (int it=0; it<4; ++it) {
    ((short8*)lds)[it*256+tid]        = ((const short8*)Ain)[it*256+tid];
    ((short8*)(lds+8192))[it*256+tid] = ((const short8*)Bin)[it*256+tid];
  }
  __syncthreads();

  f32x4 g[2][8] = {};
#pragma unroll
  for (int ks=0; ks<2; ++ks) {
    short8 af[2];
#pragma unroll
    for (int mi=0; mi<2; ++mi)
      af[mi] = frag_tile(lds, w*32 + mi*16 + l15, ks, l4);
#pragma unroll
    for (int n=0;n<8;++n) {
      short8 bf = frag_tile(lds+8192, n*16 + l15, ks, l4);
#pragma unroll
      for (int mi=0;mi<2;++mi)
        g[mi][n] = __builtin_amdgcn_mfma_f32_16x16x32_bf16(af[mi], bf, g[mi][n], 0,0,0);
    }
  }
  __syncthreads();

#pragma unroll
  for (int mi=0;mi<2;++mi)
#pragma unroll
    for (int n=0;n<8;++n)
#pragma unroll
      for (int j=0;j<4;++j) {
        int m = w*32 + mi*16 + l4*4 + j, c = n*16 + l15;
        lds[sidx(m,c)] = f2b(-g[mi][n][j]);
      }
  __syncthreads();

  u16* Sout = S + ((size_t)((op ? bh : 16+bh))*64 + ch)*16384;
#pragma unroll
  for (int it=0; it<8; ++it) {
    int task = it*256 + tid;
    int m = task>>4, gg = task&15;
    *(short8*)&Sout[m*128 + gg*8] = *(const short8*)&lds[m*128 + ((gg ^ (m&7))<<3)];
  }
}

// ---- double linear-recurrence scan over chunks, folds W = w + update ----

__global__ __launch_bounds__(256) void scan_kernel(
    u16* __restrict__ S, const float* __restrict__ mg, const float* __restrict__ d1m,
    const u16* __restrict__ w0T, const u16* __restrict__ w1T)
{
  int bidx = blockIdx.x;              // mbh*64 + eblk
  int eblk = bidx & 63;
  int mbh = bidx >> 6;                // 0..31 (0..15 = S0/w0, 16..31 = S1/w1)
  int bh = mbh & 15;
  int e = eblk*256 + threadIdx.x;
  u16* base = S + (size_t)mbh*64*16384 + e;
  float wv = b2f(((mbh < 16) ? w0T : w1T)[e]);
  const float* g1 = mg + bh*64;
  const float* g2 = d1m + bh*64;
  float mom = 0.f, upd = 0.f;
  for (int c2=0; c2<64; ++c2) {
    float s = b2f(base[(size_t)c2*16384]);
    mom = g1[c2]*mom + s;            // momentum scan
    upd = g2[c2]*upd + mom;          // update scan
    base[(size_t)c2*16384] = f2b(wv + upd);
  }
}

// ---------------- per-chunk retrieval (W preadded by scan; barrier-free) ----------------

__global__ __launch_bounds__(256) void retrieve_kernel(
    const u16* __restrict__ qn, const u16* __restrict__ W,
    const float* __restrict__ gamma, const float* __restrict__ gate,
    u16* __restrict__ vals)
{
  __shared__ __align__(16) u16 QA[64*128];    // Q rows -> silu(x) rows (wave-private)
  int bid = blockIdx.x; int bh = bid>>6, ch = bid&63;
  int b = bh>>3, h = bh&7;
  int tid = threadIdx.x;
  int w = tid>>6, lane = tid&63;
  int l15 = lane&15, l4 = lane>>4;
  const u16* W0 = W + ((size_t)bh*64 + ch)*16384;
  const u16* W1 = W + ((size_t)(16+bh)*64 + ch)*16384;
  // wave-private Q staging (own 16 rows)
#pragma unroll
  for (int it=0; it<4; ++it) {
    int task = it*64 + lane;
    int rloc = w*16 + (task>>4), g = task&15;
    int posn = ch*64 + rloc + 63;
    short8 v;
    if (posn < 4096) v = *(const short8*)&qn[((size_t)(b*4096+posn))*1024 + h*128 + g*8];
    else {
#pragma unroll
      for (int i=0;i<8;++i) v[i]=0;
    }
    *(short8*)&QA[rloc*128 + ((g ^ (rloc&7))<<3)] = v;
  }
  // x = q @ W0 (B-frags: single 16B global loads)
  f32x4 xx[8] = {};
#pragma unroll
  for (int ks=0; ks<4; ++ks) {
    short8 af = frag_row_lds128(QA, w*16 + l15, ks, l4);
    int kof = ks*32 + l4*8;
#pragma unroll
    for (int n=0;n<8;++n) {
      short8 bf = *(const short8*)&W0[(size_t)(n*16+l15)*128 + kof];
      xx[n] = __builtin_amdgcn_mfma_f32_16x16x32_bf16(af, bf, xx[n], 0,0,0);
    }
  }
  int r0 = w*16 + l4*4;
#pragma unroll
  for (int n=0;n<8;++n) {
    int c = n*16 + l15;
#pragma unroll
    for (int j=0;j<4;++j) {
      float xv = xx[n][j];
      QA[sidx(r0+j,c)] = f2b(xv * sigm(xv));
    }
  }
  // vals = silu(x) @ W1
  f32x4 vv[8] = {};
#pragma unroll
  for (int ks=0; ks<4; ++ks) {
    short8 af = frag_row_lds128(QA, w*16 + l15, ks, l4);
    int kof = ks*32 + l4*8;
#pragma unroll
    for (int n=0;n<8;++n) {
      short8 bf = *(const short8*)&W1[(size_t)(n*16+l15)*128 + kof];
      vv[n] = __builtin_amdgcn_mfma_f32_16x16x32_bf16(af, bf, vv[n], 0,0,0);
    }
  }
  // epilogue: rmsnorm over dh, *(1+gamma), *gate, store at natural pos
#pragma unroll
  for (int j=0;j<4;++j) {
    float ssq = 0.f;
#pragma unroll
    for (int n=0;n<8;++n) ssq += vv[n][j]*vv[n][j];
    ssq += __shfl_xor(ssq,1); ssq += __shfl_xor(ssq,2);
    ssq += __shfl_xor(ssq,4); ssq += __shfl_xor(ssq,8);
    float rms = rsqrtf(ssq*(1.f/128.f) + 1e-6f);
    int r = r0 + j;
    int posn = ch*64 + r + 63;
    if (posn < 4096) {
      float gt = gate[(size_t)bh*4096 + posn];
      size_t orow = ((size_t)(b*4096+posn))*1024 + h*128;
#pragma unroll
      for (int n=0;n<8;++n) {
        int c = n*16 + l15;
        vals[orow + c] = f2b(vv[n][j]*rms*(1.f + gamma[h*128+c])*gt);
      }
    }
  }
}

extern "C" void kernel_launch(void* const* d_in, const int* in_sizes, int n_in,
                              void* d_out, int out_size, void* d_ws, size_t ws_size,
                              hipStream_t stream) {
  const float* seq    = (const float*)d_in[0];
  const float* gstore = (const float*)d_in[1];
  const float* gret   = (const float*)d_in[2];
  const float* wkv    = (const float*)d_in[3];
  const float* wq     = (const float*)d_in[4];
  const float* wstep  = (const float*)d_in[5];
  const float* wmom   = (const float*)d_in[6];
  const float* wdec   = (const float*)d_in[7];
  const float* wgate  = (const float*)d_in[8];
  const float* wcomb  = (const float*)d_in[9];
  const float* gamma  = (const float*)d_in[10];
  const float* w0f    = (const float*)d_in[11];
  const float* w1f    = (const float*)d_in[12];
  float* out = (float*)d_out;
  (void)in_sizes; (void)n_in; (void)out_size; (void)ws_size;

  char* p = (char*)d_ws;
  size_t off = 0;
  auto alloc = [&](size_t bytes) -> void* {
    void* r = p + off; off += (bytes + 255) & ~(size_t)255; return r;
  };
  u16* wkvT   = (u16*)alloc((size_t)2048*1024*2);
  u16* wqT    = (u16*)alloc((size_t)1024*1024*2);
  u16* wcombT = (u16*)alloc((size_t)1024*1024*2);
  u16* w0T    = (u16*)alloc(16384*2);
  u16* w1b    = (u16*)alloc(16384*2);
  u16* w1T    = (u16*)alloc(16384*2);
  u16* ss     = (u16*)alloc((size_t)NTOK*1024*2);
  u16* sr     = (u16*)alloc((size_t)NTOK*1024*2);
  u16* kvout  = (u16*)alloc((size_t)NTOK*2048*2);
  u16* qn     = (u16*)alloc((size_t)NTOK*1024*2);
  u16* vals   = (u16*)alloc((size_t)NTOK*1024*2);
  float* lr   = (float*)alloc((size_t)16*4096*4);
  float* gate = (float*)alloc((size_t)16*4096*4);
  float* mg   = (float*)alloc(1024*4);
  float* d1m  = (float*)alloc(1024*4);
  u16* S      = (u16*)alloc((size_t)32*64*16384*2);
  u16* kTg    = (u16*)alloc((size_t)1024*8192*2);
  u16* aTg    = (u16*)alloc((size_t)1024*8192*2);
  u16* dpTg   = (u16*)alloc((size_t)1024*8192*2);
  u16* dxTg   = (u16*)alloc((size_t)1024*8192*2);

  transpose_bf16<<<dim3(512),dim3(256),0,stream>>>(wkv, wkvT, 1024, 2048);
  transpose_bf16<<<dim3(256),dim3(256),0,stream>>>(wq, wqT, 1024, 1024);
  transpose_bf16<<<dim3(256),dim3(256),0,stream>>>(wcomb, wcombT, 1024, 1024);
  smallprep<<<dim3(64),dim3(256),0,stream>>>(w0f, w1f, w0T, w1b, w1T);
  norms_kernel<<<dim3(NTOK),dim3(256),0,stream>>>(seq, gstore, gret, wstep, wgate, ss, sr, lr, gate);
  chunkgates_kernel<<<dim3(128),dim3(256),0,stream>>>(ss, wmom, wdec, mg, d1m);
  gemm_bt<<<dim3(16,64),dim3(256),0,stream>>>(ss, wkvT, kvout, 8192, 2048, 1024, 0, kTg);
  gemm_bt<<<dim3(8,64),dim3(256),0,stream>>>(sr, wqT, qn, 8192, 1024, 1024, 0, nullptr);
  mlp_fwd<<<dim3(1024),dim3(256),0,stream>>>(kvout, lr, w0T, w1T, w1b, aTg, dpTg, dxTg);
  grad_op<<<dim3(2048),dim3(256),0,stream>>>(dpTg, aTg, dxTg, kTg, S);
  scan_kernel<<<dim3(2048),dim3(256),0,stream>>>(S, mg, d1m, w0T, w1T);
  hipMemsetAsync(vals, 0, 63*1024*2, stream);
  hipMemsetAsync(vals + (size_t)4096*1024, 0, 63*1024*2, stream);
  retrieve_kernel<<<dim3(1024),dim3(256),0,stream>>>(qn, S, gamma, gate, vals);
  gemm_bt<<<dim3(8,64),dim3(256),0,stream>>>(vals, wcombT, out, 8192, 1024, 1024, 1, nullptr);
}